// Round 1
// 388.510 us; speedup vs baseline: 1.0288x; 1.0288x over previous
//
#include <hip/hip_runtime.h>
#include <cstdint>
#include <cstddef>

#define AS1 __attribute__((address_space(1)))
#define AS3 __attribute__((address_space(3)))

typedef unsigned short u16;
typedef unsigned int u32;
typedef unsigned char u8;
typedef int i32x4 __attribute__((ext_vector_type(4)));
typedef int i32x8 __attribute__((ext_vector_type(8)));
typedef float f32x4 __attribute__((ext_vector_type(4)));

constexpr int D  = 1024;   // K
constexpr int NS = 16384;  // rows of x (M)
constexpr int US = 4096;   // rows of w (N of output)
constexpr int BM = 256, BN = 256, BK = 128;  // BK in fp8 elements (= bytes)
constexpr int KT = D / BK;                   // 8 K-tiles

// ws layout: xq 16MB | wq 4MB | xsq 64KB | wsq 16KB
constexpr size_t XQ_OFF  = 0;
constexpr size_t WQ_OFF  = (size_t)NS * D;
constexpr size_t XSQ_OFF = WQ_OFF + (size_t)US * D;
constexpr size_t WSQ_OFF = XSQ_OFF + (size_t)NS * 4;

// Fused prepass: one wave per row (grid-stride), no barriers.
// Rows [0,16384) -> x (scale 1); rows [16384,20480) -> w (quantize 16*w).
// Writes e4m3 bytes + fp32 sum of squares (of the ORIGINAL values).
__global__ __launch_bounds__(256) void quant_sq(
    const float* __restrict__ x, const float* __restrict__ w,
    u8* __restrict__ xq, u8* __restrict__ wq,
    float* __restrict__ xsq, float* __restrict__ wsq) {
  const int lane = threadIdx.x & 63;
  const int wave = blockIdx.x * 4 + (threadIdx.x >> 6);
  const int nwaves = gridDim.x * 4;
  for (int row = wave; row < NS + US; row += nwaves) {
    const float* src; u8* qdst; float* sdst; int r; float qscale;
    if (row < NS) { src = x; qdst = xq; sdst = xsq; r = row; qscale = 1.0f; }
    else          { src = w; qdst = wq; sdst = wsq; r = row - NS; qscale = 16.0f; }
    const float4* s4 = (const float4*)(src + (size_t)r * D);
    u32* qrow = (u32*)(qdst + (size_t)r * D);
    float s = 0.f;
#pragma unroll
    for (int it = 0; it < 4; ++it) {
      const float4 v = s4[it * 64 + lane];
      s += v.x * v.x + v.y * v.y + v.z * v.z + v.w * v.w;
      u32 p01 = __builtin_amdgcn_cvt_pk_fp8_f32(v.x * qscale, v.y * qscale, 0, false);
      u32 w0  = __builtin_amdgcn_cvt_pk_fp8_f32(v.z * qscale, v.w * qscale, p01, true);
      qrow[it * 64 + lane] = w0;
    }
#pragma unroll
    for (int off = 32; off; off >>= 1) s += __shfl_down(s, off, 64);
    if (lane == 0) sdst[r] = s;
  }
}

// out[R][C] = xsq[R] + wsq[C] - 0.125 * sum_k e4m3(x)[R][k] * e4m3(16w)[C][k]
// 256x256 tile, 8 waves (2M x 4N), per-wave output 128x64.
// Double-buffered K-tiles (2 x 64KB LDS), counted s_waitcnt vmcnt(8) —
// prefetch loads stay in flight across raw s_barriers (T3/T4-lite).
__global__ __launch_bounds__(512, 2) void dist_gemm(
    const u8* __restrict__ xq, const u8* __restrict__ wq,
    const float* __restrict__ xsq, const float* __restrict__ wsq,
    float* __restrict__ out) {
  // buffer b at lds + b*65536: A tile 32KB (256 rows x 128B), then B tile 32KB.
  // Row = 8 chunks of 16B; chunk XOR-swizzled by (row&7) on the GLOBAL side
  // (global_load_lds dest must stay linear), un-swizzled on the read side.
  __shared__ u8 lds[2 * 65536];  // 128 KB

  const int tid = threadIdx.x;
  const int lane = tid & 63;
  const int wv = tid >> 6;      // wave 0..7
  const int wm = wv >> 2;       // 0..1  (128-row half of BM)
  const int wn = wv & 3;        // 0..3  (64-col quarter of BN)
  const int quad = lane >> 4;
  const int l15 = lane & 15;

  const int m0 = blockIdx.y * BM;  // x-row base
  const int n0 = blockIdx.x * BN;  // w-row base

  f32x4 acc[8][4];
#pragma unroll
  for (int mt = 0; mt < 8; ++mt)
#pragma unroll
    for (int nt = 0; nt < 4; ++nt)
      acc[mt][nt] = (f32x4){0.f, 0.f, 0.f, 0.f};

  // staging coords: 512 threads x 16B = 8KB sweep = 64 rows; 4 sweeps per matrix
  const int srow = tid >> 3;    // row 0..63 within a sweep
  const int sch = lane & 7;     // 16B chunk within the 128B row

  auto stage = [&](int buf, int kt) {
    u8* base = lds + buf * 65536;
    const int k0 = kt * BK;
#pragma unroll
    for (int s = 0; s < 4; ++s) {
      const int r = s * 64 + srow;
      const int cg = sch ^ (r & 7);
      const u8* ga = xq + (size_t)(m0 + r) * D + k0 + cg * 16;
      __builtin_amdgcn_global_load_lds((AS1 void*)(u8*)ga,
          (AS3 void*)(base + s * 8192 + wv * 1024), 16, 0, 0);
    }
#pragma unroll
    for (int s = 0; s < 4; ++s) {
      const int r = s * 64 + srow;
      const int cg = sch ^ (r & 7);
      const u8* gb = wq + (size_t)(n0 + r) * D + k0 + cg * 16;
      __builtin_amdgcn_global_load_lds((AS1 void*)(u8*)gb,
          (AS3 void*)(base + 32768 + s * 8192 + wv * 1024), 16, 0, 0);
    }
  };

  // Prologue: stage tiles 0 and 1; wait own tile-0 loads (8 of 16 outstanding),
  // then barrier so ALL waves' tile-0 loads are visible.
  stage(0, 0);
  stage(1, 1);
  asm volatile("s_waitcnt vmcnt(8)" ::: "memory");
  __builtin_amdgcn_sched_barrier(0);
  __builtin_amdgcn_s_barrier();
  __builtin_amdgcn_sched_barrier(0);

  for (int kt = 0; kt < KT; ++kt) {
    const u8* sA = lds + (kt & 1) * 65536;
    const u8* sB = sA + 32768;

    // B fragments for this K-tile: 4 x (2 ds_read_b128)
    i32x8 b[4];
#pragma unroll
    for (int nt = 0; nt < 4; ++nt) {
      const int n = wn * 64 + nt * 16 + l15;
      const int s = n & 7;
      const i32x4 b0 = *reinterpret_cast<const i32x4*>(sB + n * BK + ((2 * quad) ^ s) * 16);
      const i32x4 b1 = *reinterpret_cast<const i32x4*>(sB + n * BK + ((2 * quad + 1) ^ s) * 16);
      b[nt] = __builtin_shufflevector(b0, b1, 0, 1, 2, 3, 4, 5, 6, 7);
    }
#pragma unroll
    for (int mt = 0; mt < 8; ++mt) {
      const int m = wm * 128 + mt * 16 + l15;
      const int s = m & 7;
      const i32x4 a0 = *reinterpret_cast<const i32x4*>(sA + m * BK + ((2 * quad) ^ s) * 16);
      const i32x4 a1 = *reinterpret_cast<const i32x4*>(sA + m * BK + ((2 * quad + 1) ^ s) * 16);
      const i32x8 a = __builtin_shufflevector(a0, a1, 0, 1, 2, 3, 4, 5, 6, 7);
      __builtin_amdgcn_s_setprio(1);
#pragma unroll
      for (int nt = 0; nt < 4; ++nt) {
        acc[mt][nt] = __builtin_amdgcn_mfma_scale_f32_16x16x128_f8f6f4(
            a, b[nt], acc[mt][nt], /*cbsz fp8*/ 0, /*blgp fp8*/ 0,
            /*opsel_a*/ 0, 0x7F7F7F7F, /*opsel_b*/ 0, 0x7F7F7F7F);
      }
      __builtin_amdgcn_s_setprio(0);
    }

    if (kt == KT - 1) break;

    // All waves finished reading buf[kt&1] (ds_reads consumed by MFMAs above).
    __builtin_amdgcn_sched_barrier(0);
    __builtin_amdgcn_s_barrier();
    __builtin_amdgcn_sched_barrier(0);
    if (kt + 2 < KT) {
      stage(kt & 1, kt + 2);  // overwrite the just-consumed buffer
      // tile kt+1 landed when only tile kt+2's 8 loads remain outstanding
      asm volatile("s_waitcnt vmcnt(8)" ::: "memory");
    } else {
      asm volatile("s_waitcnt vmcnt(0)" ::: "memory");
    }
    __builtin_amdgcn_sched_barrier(0);
    __builtin_amdgcn_s_barrier();
    __builtin_amdgcn_sched_barrier(0);
  }

  // ---- epilogue: C/D layout col = lane&15 (n), row = quad*4 + reg (m) ----
#pragma unroll
  for (int mt = 0; mt < 8; ++mt) {
    const int R0 = m0 + wm * 128 + mt * 16 + quad * 4;
#pragma unroll
    for (int nt = 0; nt < 4; ++nt) {
      const int C = n0 + wn * 64 + nt * 16 + l15;
      const float wsv = wsq[C];
#pragma unroll
      for (int r = 0; r < 4; ++r) {
        const int R = R0 + r;
        out[(size_t)R * US + C] = xsq[R] + wsv - 0.125f * acc[mt][nt][r];
      }
    }
  }
}

extern "C" void kernel_launch(void* const* d_in, const int* in_sizes, int n_in,
                              void* d_out, int out_size, void* d_ws, size_t ws_size,
                              hipStream_t stream) {
  const float* x = (const float*)d_in[0];  // [16384, 1024]
  const float* w = (const float*)d_in[1];  // [4096, 1024]
  float* out = (float*)d_out;              // [16384, 4096]
  char* ws = (char*)d_ws;                  // ~20.1 MB used

  u8* xq = (u8*)(ws + XQ_OFF);
  u8* wq = (u8*)(ws + WQ_OFF);
  float* xsq = (float*)(ws + XSQ_OFF);
  float* wsq = (float*)(ws + WSQ_OFF);

  quant_sq<<<dim3(640), dim3(256), 0, stream>>>(x, w, xq, wq, xsq, wsq);
  dist_gemm<<<dim3(US / BN, NS / BM), dim3(512), 0, stream>>>(xq, wq, xsq, wsq, out);
}

// Round 2
// 383.125 us; speedup vs baseline: 1.0433x; 1.0141x over previous
//
#include <hip/hip_runtime.h>
#include <cstdint>
#include <cstddef>

#define AS1 __attribute__((address_space(1)))
#define AS3 __attribute__((address_space(3)))

typedef unsigned int u32;
typedef unsigned char u8;
typedef int i32x4 __attribute__((ext_vector_type(4)));
typedef int i32x8 __attribute__((ext_vector_type(8)));
typedef float f32x4 __attribute__((ext_vector_type(4)));

constexpr int D  = 1024;   // K
constexpr int NS = 16384;  // rows of x (M)
constexpr int US = 4096;   // rows of w (N of output)
constexpr int BM = 256, BN = 256, BK = 128;  // BK in fp8 elements (= bytes)
constexpr int KT = D / BK;                   // 8 K-tiles

// ws layout: xq 16MB | wq 4MB | xsq 64KB | wsq 16KB
constexpr size_t XQ_OFF  = 0;
constexpr size_t WQ_OFF  = (size_t)NS * D;
constexpr size_t XSQ_OFF = WQ_OFF + (size_t)US * D;
constexpr size_t WSQ_OFF = XSQ_OFF + (size_t)NS * 4;

// Fused prepass: one wave per row (grid-stride), no barriers.
__global__ __launch_bounds__(256) void quant_sq(
    const float* __restrict__ x, const float* __restrict__ w,
    u8* __restrict__ xq, u8* __restrict__ wq,
    float* __restrict__ xsq, float* __restrict__ wsq) {
  const int lane = threadIdx.x & 63;
  const int wave = blockIdx.x * 4 + (threadIdx.x >> 6);
  const int nwaves = gridDim.x * 4;
  for (int row = wave; row < NS + US; row += nwaves) {
    const float* src; u8* qdst; float* sdst; int r; float qscale;
    if (row < NS) { src = x; qdst = xq; sdst = xsq; r = row; qscale = 1.0f; }
    else          { src = w; qdst = wq; sdst = wsq; r = row - NS; qscale = 16.0f; }
    const float4* s4 = (const float4*)(src + (size_t)r * D);
    u32* qrow = (u32*)(qdst + (size_t)r * D);
    float s = 0.f;
#pragma unroll
    for (int it = 0; it < 4; ++it) {
      const float4 v = s4[it * 64 + lane];
      s += v.x * v.x + v.y * v.y + v.z * v.z + v.w * v.w;
      u32 p01 = __builtin_amdgcn_cvt_pk_fp8_f32(v.x * qscale, v.y * qscale, 0, false);
      u32 w0  = __builtin_amdgcn_cvt_pk_fp8_f32(v.z * qscale, v.w * qscale, p01, true);
      qrow[it * 64 + lane] = w0;
    }
#pragma unroll
    for (int off = 32; off; off >>= 1) s += __shfl_down(s, off, 64);
    if (lane == 0) sdst[r] = s;
  }
}

// out[R][C] = xsq[R] + wsq[C] - 0.125 * sum_k e4m3(x)[R][k] * e4m3(16w)[C][k]
// 256x256 tile, 8 waves (2M x 4N), per-wave output 128x64.
// m201-style 8-phase schedule: per K-tile 4 phases of {ds-read subtile ||
// 0-3 global_load_lds -> s_barrier -> lgkmcnt(0) -> 8 MFMA -> s_barrier};
// vmcnt(6) once per K-tile boundary. Staging of tile t+2 into buf[t&1]
// targets only regions whose tile-t reads completed >=1 phase (barrier) ago:
//   phase0: tile t+1 A-sweeps 1,3 -> other buffer (fully consumed last tile)
//   phase1: tile t+2 B-sweeps 0,1,2  (B fully read in phase0)
//   phase2: tile t+2 B-sweep 3, A-sweeps 0,2  (A rows (r&127)<64 read in ph0/1)
__global__ __launch_bounds__(512, 2) void dist_gemm(
    const u8* __restrict__ xq, const u8* __restrict__ wq,
    const float* __restrict__ xsq, const float* __restrict__ wsq,
    float* __restrict__ out) {
  __shared__ u8 lds[2 * 65536];  // per buf: A 32KB (256 rows x 128B) | B 32KB

  const int tid = threadIdx.x;
  const int lane = tid & 63;
  const int wv = tid >> 6;      // wave 0..7
  const int wm = wv >> 2;       // 0..1  (128-row half of BM)
  const int wn = wv & 3;        // 0..3  (64-col quarter of BN)
  const int quad = lane >> 4;
  const int l15 = lane & 15;

  const int m0 = blockIdx.y * BM;
  const int n0 = blockIdx.x * BN;

  // staging coords: one global_load_lds per thread covers a 64-row sweep (8KB)
  const int srow = tid >> 3;    // row 0..63 within a sweep
  const int sch = lane & 7;     // 16B chunk within the 128B row

  f32x4 acc[8][4];
#pragma unroll
  for (int mt = 0; mt < 8; ++mt)
#pragma unroll
    for (int nt = 0; nt < 4; ++nt) acc[mt][nt] = (f32x4){0.f, 0.f, 0.f, 0.f};

  auto stageA = [&](int buf, int kt, int sw) {
    const int r = sw * 64 + srow;
    const int cg = sch ^ (r & 7);   // XOR-swizzle applied on GLOBAL side
    const u8* g = xq + (size_t)(m0 + r) * D + kt * BK + cg * 16;
    __builtin_amdgcn_global_load_lds((AS1 void*)(u8*)g,
        (AS3 void*)(lds + buf * 65536 + sw * 8192 + wv * 1024), 16, 0, 0);
  };
  auto stageB = [&](int buf, int kt, int sw) {
    const int r = sw * 64 + srow;
    const int cg = sch ^ (r & 7);
    const u8* g = wq + (size_t)(n0 + r) * D + kt * BK + cg * 16;
    __builtin_amdgcn_global_load_lds((AS1 void*)(u8*)g,
        (AS3 void*)(lds + buf * 65536 + 32768 + sw * 8192 + wv * 1024), 16, 0, 0);
  };
  auto ldfrag = [&](const u8* mat, int row) -> i32x8 {
    const int s = row & 7;
    const i32x4 f0 = *reinterpret_cast<const i32x4*>(mat + row * BK + ((2 * quad) ^ s) * 16);
    const i32x4 f1 = *reinterpret_cast<const i32x4*>(mat + row * BK + ((2 * quad + 1) ^ s) * 16);
    return __builtin_shufflevector(f0, f1, 0, 1, 2, 3, 4, 5, 6, 7);
  };

  // ---- prologue: stage tiles 0 and 1 fully; wait tile 0 (8 newest = tile 1) ----
#pragma unroll
  for (int sw = 0; sw < 4; ++sw) stageA(0, 0, sw);
#pragma unroll
  for (int sw = 0; sw < 4; ++sw) stageB(0, 0, sw);
#pragma unroll
  for (int sw = 0; sw < 4; ++sw) stageA(1, 1, sw);
#pragma unroll
  for (int sw = 0; sw < 4; ++sw) stageB(1, 1, sw);
  asm volatile("s_waitcnt vmcnt(8)" ::: "memory");
  __builtin_amdgcn_sched_barrier(0);
  __builtin_amdgcn_s_barrier();
  __builtin_amdgcn_sched_barrier(0);

#define MM(MT, NT, AF) \
  acc[MT][NT] = __builtin_amdgcn_mfma_scale_f32_16x16x128_f8f6f4( \
      AF, bf[NT], acc[MT][NT], 0, 0, 0, 0x7F7F7F7F, 0, 0x7F7F7F7F)

#define OPEN_PHASE() do { \
    __builtin_amdgcn_sched_barrier(0); \
    __builtin_amdgcn_s_barrier(); \
    asm volatile("s_waitcnt lgkmcnt(0)" ::: "memory"); \
    __builtin_amdgcn_sched_barrier(0); \
    __builtin_amdgcn_s_setprio(1); } while (0)

#define CLOSE_PHASE() do { \
    __builtin_amdgcn_s_setprio(0); \
    __builtin_amdgcn_sched_barrier(0); \
    __builtin_amdgcn_s_barrier(); \
    __builtin_amdgcn_sched_barrier(0); } while (0)

#pragma unroll
  for (int t = 0; t < KT; ++t) {
    const u8* sA = lds + (t & 1) * 65536;
    const u8* sB = sA + 32768;
    const int nb = (t + 1) & 1;
    const int ar = wm * 128 + l15;
    const int br = wn * 64 + l15;

    i32x8 bf[4];

    // ---------- phase 0: B all (8 reads) + A mt{0,1} (4 reads) ----------
    {
      bf[0] = ldfrag(sB, br);
      bf[1] = ldfrag(sB, br + 16);
      bf[2] = ldfrag(sB, br + 32);
      bf[3] = ldfrag(sB, br + 48);
      i32x8 a0 = ldfrag(sA, ar);
      i32x8 a1 = ldfrag(sA, ar + 16);
      if (t >= 1 && t + 1 < KT) { stageA(nb, t + 1, 1); stageA(nb, t + 1, 3); }
      OPEN_PHASE();
      MM(0, 0, a0); MM(0, 1, a0); MM(0, 2, a0); MM(0, 3, a0);
      MM(1, 0, a1); MM(1, 1, a1); MM(1, 2, a1); MM(1, 3, a1);
      CLOSE_PHASE();
    }
    // ---------- phase 1: A mt{2,3} ----------
    {
      i32x8 a0 = ldfrag(sA, ar + 32);
      i32x8 a1 = ldfrag(sA, ar + 48);
      if (t + 2 < KT) { stageB(t & 1, t + 2, 0); stageB(t & 1, t + 2, 1); stageB(t & 1, t + 2, 2); }
      OPEN_PHASE();
      MM(2, 0, a0); MM(2, 1, a0); MM(2, 2, a0); MM(2, 3, a0);
      MM(3, 0, a1); MM(3, 1, a1); MM(3, 2, a1); MM(3, 3, a1);
      CLOSE_PHASE();
    }
    // ---------- phase 2: A mt{4,5} ----------
    {
      i32x8 a0 = ldfrag(sA, ar + 64);
      i32x8 a1 = ldfrag(sA, ar + 80);
      if (t + 2 < KT) { stageB(t & 1, t + 2, 3); stageA(t & 1, t + 2, 0); stageA(t & 1, t + 2, 2); }
      OPEN_PHASE();
      MM(4, 0, a0); MM(4, 1, a0); MM(4, 2, a0); MM(4, 3, a0);
      MM(5, 0, a1); MM(5, 1, a1); MM(5, 2, a1); MM(5, 3, a1);
      CLOSE_PHASE();
    }
    // ---------- phase 3: A mt{6,7}; vmcnt(6) at tile boundary ----------
    {
      i32x8 a0 = ldfrag(sA, ar + 96);
      i32x8 a1 = ldfrag(sA, ar + 112);
      OPEN_PHASE();
      MM(6, 0, a0); MM(6, 1, a0); MM(6, 2, a0); MM(6, 3, a0);
      MM(7, 0, a1); MM(7, 1, a1); MM(7, 2, a1); MM(7, 3, a1);
      __builtin_amdgcn_s_setprio(0);
      __builtin_amdgcn_sched_barrier(0);
      if (t < KT - 1) {
        if (t + 2 < KT) asm volatile("s_waitcnt vmcnt(6)" ::: "memory");
        else            asm volatile("s_waitcnt vmcnt(0)" ::: "memory");
        __builtin_amdgcn_sched_barrier(0);
        __builtin_amdgcn_s_barrier();
        __builtin_amdgcn_sched_barrier(0);
      }
    }
  }

  // ---- epilogue: C/D layout col = lane&15 (n), row = quad*4 + reg (m) ----
#pragma unroll
  for (int mt = 0; mt < 8; ++mt) {
    const int R0 = m0 + wm * 128 + mt * 16 + quad * 4;
#pragma unroll
    for (int nt = 0; nt < 4; ++nt) {
      const int C = n0 + wn * 64 + nt * 16 + l15;
      const float wsv = wsq[C];
#pragma unroll
      for (int r = 0; r < 4; ++r) {
        const int R = R0 + r;
        out[(size_t)R * US + C] = xsq[R] + wsv - 0.125f * acc[mt][nt][r];
      }
    }
  }
}

extern "C" void kernel_launch(void* const* d_in, const int* in_sizes, int n_in,
                              void* d_out, int out_size, void* d_ws, size_t ws_size,
                              hipStream_t stream) {
  const float* x = (const float*)d_in[0];  // [16384, 1024]
  const float* w = (const float*)d_in[1];  // [4096, 1024]
  float* out = (float*)d_out;              // [16384, 4096]
  char* ws = (char*)d_ws;                  // ~20.1 MB used

  u8* xq = (u8*)(ws + XQ_OFF);
  u8* wq = (u8*)(ws + WQ_OFF);
  float* xsq = (float*)(ws + XSQ_OFF);
  float* wsq = (float*)(ws + WSQ_OFF);

  quant_sq<<<dim3(640), dim3(256), 0, stream>>>(x, w, xq, wq, xsq, wsq);
  dist_gemm<<<dim3(US / BN, NS / BM), dim3(512), 0, stream>>>(xq, wq, xsq, wsq, out);
}

// Round 3
// 376.866 us; speedup vs baseline: 1.0606x; 1.0166x over previous
//
#include <hip/hip_runtime.h>
#include <cstdint>
#include <cstddef>

#define AS1 __attribute__((address_space(1)))
#define AS3 __attribute__((address_space(3)))

typedef unsigned int u32;
typedef unsigned char u8;
typedef int i32x4 __attribute__((ext_vector_type(4)));
typedef int i32x8 __attribute__((ext_vector_type(8)));
typedef float f32x4 __attribute__((ext_vector_type(4)));

constexpr int D  = 1024;   // K
constexpr int NS = 16384;  // rows of x (M)
constexpr int US = 4096;   // rows of w (N of output)
constexpr int BM = 256, BN = 256, BK = 128;  // BK in fp8 elements (= bytes)
constexpr int KT = D / BK;                   // 8 K-tiles

// ws layout: xq 16MB | wq 4MB | xsq 64KB | wsq 16KB
constexpr size_t XQ_OFF  = 0;
constexpr size_t WQ_OFF  = (size_t)NS * D;
constexpr size_t XSQ_OFF = WQ_OFF + (size_t)US * D;
constexpr size_t WSQ_OFF = XSQ_OFF + (size_t)NS * 4;

// Fused prepass: one wave per row (grid-stride), no barriers.
__global__ __launch_bounds__(256) void quant_sq(
    const float* __restrict__ x, const float* __restrict__ w,
    u8* __restrict__ xq, u8* __restrict__ wq,
    float* __restrict__ xsq, float* __restrict__ wsq) {
  const int lane = threadIdx.x & 63;
  const int wave = blockIdx.x * 4 + (threadIdx.x >> 6);
  const int nwaves = gridDim.x * 4;
  for (int row = wave; row < NS + US; row += nwaves) {
    const float* src; u8* qdst; float* sdst; int r; float qscale;
    if (row < NS) { src = x; qdst = xq; sdst = xsq; r = row; qscale = 1.0f; }
    else          { src = w; qdst = wq; sdst = wsq; r = row - NS; qscale = 16.0f; }
    const float4* s4 = (const float4*)(src + (size_t)r * D);
    u32* qrow = (u32*)(qdst + (size_t)r * D);
    float s = 0.f;
#pragma unroll
    for (int it = 0; it < 4; ++it) {
      const float4 v = s4[it * 64 + lane];
      s += v.x * v.x + v.y * v.y + v.z * v.z + v.w * v.w;
      u32 p01 = __builtin_amdgcn_cvt_pk_fp8_f32(v.x * qscale, v.y * qscale, 0, false);
      u32 w0  = __builtin_amdgcn_cvt_pk_fp8_f32(v.z * qscale, v.w * qscale, p01, true);
      qrow[it * 64 + lane] = w0;
    }
#pragma unroll
    for (int off = 32; off; off >>= 1) s += __shfl_down(s, off, 64);
    if (lane == 0) sdst[r] = s;
  }
}

// out[R][C] = xsq[R] + wsq[C] - 0.125 * sum_k e4m3(x)[R][k] * e4m3(16w)[C][k]
// 256x256 tile, 8 waves (2M x 4N), per-wave output 128x64.
// m201-style phased schedule with counted vmcnt; tile 7 peeled barrier-free
// with the epilogue interleaved into its MFMA phases.
__global__ __launch_bounds__(512, 2) void dist_gemm(
    const u8* __restrict__ xq, const u8* __restrict__ wq,
    const float* __restrict__ xsq, const float* __restrict__ wsq,
    float* __restrict__ out) {
  __shared__ u8 lds[2 * 65536];  // per buf: A 32KB (256 rows x 128B) | B 32KB

  const int tid = threadIdx.x;
  const int lane = tid & 63;
  const int wv = tid >> 6;      // wave 0..7
  const int wm = wv >> 2;       // 0..1  (128-row half of BM)
  const int wn = wv & 3;        // 0..3  (64-col quarter of BN)
  const int quad = lane >> 4;
  const int l15 = lane & 15;

  const int m0 = blockIdx.y * BM;
  const int n0 = blockIdx.x * BN;

  const int srow = tid >> 3;    // row 0..63 within a 64-row staging sweep
  const int sch = lane & 7;     // 16B chunk within the 128B row

  f32x4 acc[8][4];
#pragma unroll
  for (int mt = 0; mt < 8; ++mt)
#pragma unroll
    for (int nt = 0; nt < 4; ++nt) acc[mt][nt] = (f32x4){0.f, 0.f, 0.f, 0.f};

  auto stageA = [&](int buf, int kt, int sw) {
    const int r = sw * 64 + srow;
    const int cg = sch ^ (r & 7);   // XOR-swizzle applied on GLOBAL side
    const u8* g = xq + (size_t)(m0 + r) * D + kt * BK + cg * 16;
    __builtin_amdgcn_global_load_lds((AS1 void*)(u8*)g,
        (AS3 void*)(lds + buf * 65536 + sw * 8192 + wv * 1024), 16, 0, 0);
  };
  auto stageB = [&](int buf, int kt, int sw) {
    const int r = sw * 64 + srow;
    const int cg = sch ^ (r & 7);
    const u8* g = wq + (size_t)(n0 + r) * D + kt * BK + cg * 16;
    __builtin_amdgcn_global_load_lds((AS1 void*)(u8*)g,
        (AS3 void*)(lds + buf * 65536 + 32768 + sw * 8192 + wv * 1024), 16, 0, 0);
  };
  auto ldfrag = [&](const u8* mat, int row) -> i32x8 {
    const int s = row & 7;
    const i32x4 f0 = *reinterpret_cast<const i32x4*>(mat + row * BK + ((2 * quad) ^ s) * 16);
    const i32x4 f1 = *reinterpret_cast<const i32x4*>(mat + row * BK + ((2 * quad + 1) ^ s) * 16);
    return __builtin_shufflevector(f0, f1, 0, 1, 2, 3, 4, 5, 6, 7);
  };

  // ---- prologue: phase-0 needs (A sweeps 0,2 + all B of tile 0) first ----
  stageA(0, 0, 0); stageA(0, 0, 2);
#pragma unroll
  for (int sw = 0; sw < 4; ++sw) stageB(0, 0, sw);
  stageA(0, 0, 1); stageA(0, 0, 3);
#pragma unroll
  for (int sw = 0; sw < 4; ++sw) stageA(1, 1, sw);
#pragma unroll
  for (int sw = 0; sw < 4; ++sw) stageB(1, 1, sw);
  asm volatile("s_waitcnt vmcnt(10)" ::: "memory");  // first 6 loads landed
  __builtin_amdgcn_sched_barrier(0);
  __builtin_amdgcn_s_barrier();
  __builtin_amdgcn_sched_barrier(0);

#define MM(MT, NT, AF) \
  acc[MT][NT] = __builtin_amdgcn_mfma_scale_f32_16x16x128_f8f6f4( \
      AF, bf[NT], acc[MT][NT], 0, 0, 0, 0x7F7F7F7F, 0, 0x7F7F7F7F)

#define OPEN_PHASE() do { \
    __builtin_amdgcn_sched_barrier(0); \
    __builtin_amdgcn_s_barrier(); \
    asm volatile("s_waitcnt lgkmcnt(0)" ::: "memory"); \
    __builtin_amdgcn_sched_barrier(0); \
    __builtin_amdgcn_s_setprio(1); } while (0)

#define CLOSE_PHASE() do { \
    __builtin_amdgcn_s_setprio(0); \
    __builtin_amdgcn_sched_barrier(0); \
    __builtin_amdgcn_s_barrier(); \
    __builtin_amdgcn_sched_barrier(0); } while (0)

#pragma unroll
  for (int t = 0; t < KT - 1; ++t) {
    const u8* sA = lds + (t & 1) * 65536;
    const u8* sB = sA + 32768;
    const int nb = (t + 1) & 1;
    const int ar = wm * 128 + l15;
    const int br = wn * 64 + l15;

    i32x8 bf[4];

    // ---------- phase 0: B all (8 reads) + A mt{0,1} ----------
    {
      bf[0] = ldfrag(sB, br);
      bf[1] = ldfrag(sB, br + 16);
      bf[2] = ldfrag(sB, br + 32);
      bf[3] = ldfrag(sB, br + 48);
      i32x8 a0 = ldfrag(sA, ar);
      i32x8 a1 = ldfrag(sA, ar + 16);
      if (t >= 1) { stageA(nb, t + 1, 1); stageA(nb, t + 1, 3); }
      OPEN_PHASE();
      MM(0, 0, a0); MM(0, 1, a0); MM(0, 2, a0); MM(0, 3, a0);
      MM(1, 0, a1); MM(1, 1, a1); MM(1, 2, a1); MM(1, 3, a1);
      CLOSE_PHASE();
    }
    // ---------- phase 1: A mt{2,3} ----------
    {
      i32x8 a0 = ldfrag(sA, ar + 32);
      i32x8 a1 = ldfrag(sA, ar + 48);
      if (t + 2 < KT) { stageB(t & 1, t + 2, 0); stageB(t & 1, t + 2, 1); stageB(t & 1, t + 2, 2); }
      OPEN_PHASE();
      MM(2, 0, a0); MM(2, 1, a0); MM(2, 2, a0); MM(2, 3, a0);
      MM(3, 0, a1); MM(3, 1, a1); MM(3, 2, a1); MM(3, 3, a1);
      CLOSE_PHASE();
    }
    // ---------- phase 2: A mt{4,5} ----------
    {
      if (t == 0) {  // ensure tile-0 A sweeps 1,3 (issued 7th/8th) landed
        asm volatile("s_waitcnt vmcnt(11)" ::: "memory");
        __builtin_amdgcn_sched_barrier(0);
      }
      i32x8 a0 = ldfrag(sA, ar + 64);
      i32x8 a1 = ldfrag(sA, ar + 80);
      if (t + 2 < KT) { stageB(t & 1, t + 2, 3); stageA(t & 1, t + 2, 0); stageA(t & 1, t + 2, 2); }
      OPEN_PHASE();
      MM(4, 0, a0); MM(4, 1, a0); MM(4, 2, a0); MM(4, 3, a0);
      MM(5, 0, a1); MM(5, 1, a1); MM(5, 2, a1); MM(5, 3, a1);
      CLOSE_PHASE();
    }
    // ---------- phase 3: A mt{6,7}; counted vmcnt at tile boundary ----------
    {
      i32x8 a0 = ldfrag(sA, ar + 96);
      i32x8 a1 = ldfrag(sA, ar + 112);
      OPEN_PHASE();
      MM(6, 0, a0); MM(6, 1, a0); MM(6, 2, a0); MM(6, 3, a0);
      MM(7, 0, a1); MM(7, 1, a1); MM(7, 2, a1); MM(7, 3, a1);
      __builtin_amdgcn_s_setprio(0);
      __builtin_amdgcn_sched_barrier(0);
      if (t + 2 < KT) asm volatile("s_waitcnt vmcnt(6)" ::: "memory");
      else            asm volatile("s_waitcnt vmcnt(0)" ::: "memory");
      __builtin_amdgcn_sched_barrier(0);
      __builtin_amdgcn_s_barrier();
      __builtin_amdgcn_sched_barrier(0);
    }
  }

  // ---- peeled tile 7: no staging in flight -> barrier-free; epilogue
  //      loads/stores interleaved under the final MFMA clusters ----
  {
    const u8* sA = lds + 65536;  // tile 7 -> buffer 1
    const u8* sB = sA + 32768;
    const int ar = wm * 128 + l15;
    const int br = wn * 64 + l15;

    float wsv[4];
#pragma unroll
    for (int nt = 0; nt < 4; ++nt) wsv[nt] = wsq[n0 + wn * 64 + nt * 16 + l15];

    i32x8 bf[4];
    bf[0] = ldfrag(sB, br);
    bf[1] = ldfrag(sB, br + 16);
    bf[2] = ldfrag(sB, br + 32);
    bf[3] = ldfrag(sB, br + 48);

    auto xs_of = [&](int mt) -> f32x4 {
      return *reinterpret_cast<const f32x4*>(xsq + m0 + wm * 128 + mt * 16 + quad * 4);
    };
    auto store2 = [&](int mt, const f32x4 xs) {
      const int R0 = m0 + wm * 128 + mt * 16 + quad * 4;
#pragma unroll
      for (int nt = 0; nt < 4; ++nt) {
        const int C = n0 + wn * 64 + nt * 16 + l15;
#pragma unroll
        for (int r = 0; r < 4; ++r)
          out[(size_t)(R0 + r) * US + C] = xs[r] + wsv[nt] - 0.125f * acc[mt][nt][r];
      }
    };

    f32x4 xs0 = xs_of(0), xs1 = xs_of(1);
    {
      i32x8 a0 = ldfrag(sA, ar);
      i32x8 a1 = ldfrag(sA, ar + 16);
      __builtin_amdgcn_s_setprio(1);
      MM(0, 0, a0); MM(0, 1, a0); MM(0, 2, a0); MM(0, 3, a0);
      MM(1, 0, a1); MM(1, 1, a1); MM(1, 2, a1); MM(1, 3, a1);
      __builtin_amdgcn_s_setprio(0);
    }
    f32x4 xs2 = xs_of(2), xs3 = xs_of(3);
    {
      i32x8 a0 = ldfrag(sA, ar + 32);
      i32x8 a1 = ldfrag(sA, ar + 48);
      __builtin_amdgcn_s_setprio(1);
      MM(2, 0, a0); MM(2, 1, a0); MM(2, 2, a0); MM(2, 3, a0);
      MM(3, 0, a1); MM(3, 1, a1); MM(3, 2, a1); MM(3, 3, a1);
      __builtin_amdgcn_s_setprio(0);
    }
    store2(0, xs0); store2(1, xs1);
    f32x4 xs4 = xs_of(4), xs5 = xs_of(5);
    {
      i32x8 a0 = ldfrag(sA, ar + 64);
      i32x8 a1 = ldfrag(sA, ar + 80);
      __builtin_amdgcn_s_setprio(1);
      MM(4, 0, a0); MM(4, 1, a0); MM(4, 2, a0); MM(4, 3, a0);
      MM(5, 0, a1); MM(5, 1, a1); MM(5, 2, a1); MM(5, 3, a1);
      __builtin_amdgcn_s_setprio(0);
    }
    store2(2, xs2); store2(3, xs3);
    f32x4 xs6 = xs_of(6), xs7 = xs_of(7);
    {
      i32x8 a0 = ldfrag(sA, ar + 96);
      i32x8 a1 = ldfrag(sA, ar + 112);
      __builtin_amdgcn_s_setprio(1);
      MM(6, 0, a0); MM(6, 1, a0); MM(6, 2, a0); MM(6, 3, a0);
      MM(7, 0, a1); MM(7, 1, a1); MM(7, 2, a1); MM(7, 3, a1);
      __builtin_amdgcn_s_setprio(0);
    }
    store2(4, xs4); store2(5, xs5);
    store2(6, xs6); store2(7, xs7);
  }
}

extern "C" void kernel_launch(void* const* d_in, const int* in_sizes, int n_in,
                              void* d_out, int out_size, void* d_ws, size_t ws_size,
                              hipStream_t stream) {
  const float* x = (const float*)d_in[0];  // [16384, 1024]
  const float* w = (const float*)d_in[1];  // [4096, 1024]
  float* out = (float*)d_out;              // [16384, 4096]
  char* ws = (char*)d_ws;                  // ~20.1 MB used

  u8* xq = (u8*)(ws + XQ_OFF);
  u8* wq = (u8*)(ws + WQ_OFF);
  float* xsq = (float*)(ws + XSQ_OFF);
  float* wsq = (float*)(ws + WSQ_OFF);

  quant_sq<<<dim3(1280), dim3(256), 0, stream>>>(x, w, xq, wq, xsq, wsq);
  dist_gemm<<<dim3(US / BN, NS / BM), dim3(512), 0, stream>>>(xq, wq, xsq, wsq, out);
}